// Round 17
// baseline (2361.300 us; speedup 1.0000x reference)
//
#include <hip/hip_runtime.h>
#include <math.h>

#define N_NODES 50000
#define N_EDGES 1600000
#define NGRAPH  512
#define HID     128
#define EDIM    64
#define NCONV   4
#define MAXWI   150064   // max worklist entries (E/16 + N) + pad
#define NPAD    (N_NODES + 32)   // padded node count for nodeproj overrun
#define EGRID   2560     // edge kernel grid
#define LOG2E   1.4426950408889634f
#define LN2     0.6931471805599453f

typedef __attribute__((ext_vector_type(8))) short short8;
typedef __attribute__((ext_vector_type(4))) float f32x4;
typedef unsigned int  u32;
typedef unsigned short u16;

#define MFMA16(a, b, c) __builtin_amdgcn_mfma_f32_16x16x32_bf16(a, b, c, 0, 0, 0)

// inputs pre-scaled by log2e
__device__ __forceinline__ float fsig2(float x) {
  return __builtin_amdgcn_rcpf(1.f + __builtin_amdgcn_exp2f(-x));
}
__device__ __forceinline__ float fsp2(float x) {   // = log2e * softplus(x/log2e)
  return fmaxf(x, 0.f) + __builtin_amdgcn_logf(1.f + __builtin_amdgcn_exp2f(-fabsf(x)));
}
__device__ __forceinline__ u16 f2bf(float x) {
  u32 u = __float_as_uint(x);
  return (u16)((u + 0x7fff + ((u >> 16) & 1)) >> 16);
}
__device__ __forceinline__ u32 f2bf_pack(float lo, float hi) {
  u32 a = __float_as_uint(lo), b = __float_as_uint(hi);
  u32 ra = (a + 0x7fff + ((a >> 16) & 1)) >> 16;
  u32 rb = (b + 0x7fff + ((b >> 16) & 1)) & 0xffff0000u;
  return ra | rb;
}
__device__ __forceinline__ short8 cvt8(float4 a, float4 b) {
  union { short8 s; u32 u[4]; } r;
  r.u[0] = f2bf_pack(a.x, a.y);
  r.u[1] = f2bf_pack(a.z, a.w);
  r.u[2] = f2bf_pack(b.x, b.y);
  r.u[3] = f2bf_pack(b.z, b.w);
  return r.s;
}

// ---------------- embed ----------------
__global__ __launch_bounds__(256) void k_embed(const float* __restrict__ x,
                                               const float* __restrict__ Wemb,
                                               const float* __restrict__ bemb,
                                               float* __restrict__ h,
                                               u16* __restrict__ hb, u16* __restrict__ hlo) {
  int i = blockIdx.x * blockDim.x + threadIdx.x;
  if (i >= N_NODES * HID) return;
  int n = i >> 7, c = i & 127;
  const float* xr = x + (size_t)n * 9;
  float acc = bemb[c];
#pragma unroll
  for (int k = 0; k < 9; k++) acc = fmaf(xr[k], Wemb[k * HID + c], acc);
  h[i] = acc;
  u16 hi16 = f2bf(acc);
  hb[i] = hi16;
  hlo[i] = f2bf(acc - __uint_as_float((u32)hi16 << 16));
}

// ---------------- CSR build ----------------
__global__ __launch_bounds__(256) void k_count(const int* __restrict__ ei, int* __restrict__ cnt) {
  int e = blockIdx.x * blockDim.x + threadIdx.x;
  if (e >= N_EDGES) return;
  atomicAdd(&cnt[ei[N_EDGES + e]], 1);
}

__global__ __launch_bounds__(256) void k_scan1(const int* __restrict__ cnt, int* __restrict__ bsum) {
  __shared__ int s[256];
  int i = blockIdx.x * 256 + threadIdx.x;
  s[threadIdx.x] = (i < N_NODES) ? cnt[i] : 0;
  __syncthreads();
  for (int o = 128; o > 0; o >>= 1) {
    if (threadIdx.x < o) s[threadIdx.x] += s[threadIdx.x + o];
    __syncthreads();
  }
  if (threadIdx.x == 0) bsum[blockIdx.x] = s[0];
}

__global__ __launch_bounds__(256) void k_scan2(int* __restrict__ bsum, int nb) {
  __shared__ int s[256];
  int tid = threadIdx.x;
  s[tid] = (tid < nb) ? bsum[tid] : 0;
  __syncthreads();
  for (int o = 1; o < 256; o <<= 1) {
    int t = (tid >= o) ? s[tid - o] : 0;
    __syncthreads();
    s[tid] += t;
    __syncthreads();
  }
  if (tid < nb) bsum[tid] = (tid == 0) ? 0 : s[tid - 1];
}

__global__ __launch_bounds__(256) void k_scan3(const int* __restrict__ cnt, const int* __restrict__ bsum,
                                               int* __restrict__ row_start, float* __restrict__ inv) {
  __shared__ int s[256];
  int i = blockIdx.x * 256 + threadIdx.x;
  int v = (i < N_NODES) ? cnt[i] : 0;
  s[threadIdx.x] = v;
  __syncthreads();
  for (int o = 1; o < 256; o <<= 1) {
    int t = (threadIdx.x >= o) ? s[threadIdx.x - o] : 0;
    __syncthreads();
    s[threadIdx.x] += t;
    __syncthreads();
  }
  if (i < N_NODES) {
    row_start[i + 1] = s[threadIdx.x] + bsum[blockIdx.x];
    inv[i] = 1.0f / (float)max(v, 1);
    if (i == 0) row_start[0] = 0;
  }
}

__global__ __launch_bounds__(256) void k_fill(const int* __restrict__ ei, const int* __restrict__ row_start,
                                              int* __restrict__ cur, int* __restrict__ eids,
                                              int* __restrict__ esrc) {
  int e = blockIdx.x * blockDim.x + threadIdx.x;
  if (e < 64) {
    eids[N_EDGES + e] = 0;
    esrc[N_EDGES + e] = 0;
  }
  if (e >= N_EDGES) return;
  int s = ei[e], d = ei[N_EDGES + e];
  int pos = row_start[d] + atomicAdd(&cur[d], 1);
  eids[pos] = e;
  esrc[pos] = s;
}

// ---------------- worklist build ----------------
__global__ __launch_bounds__(256) void k_tilecnt(const int* __restrict__ row_start,
                                                 int* __restrict__ tcnt) {
  int i = blockIdx.x * 256 + threadIdx.x;
  if (i >= N_NODES) return;
  tcnt[i] = (row_start[i + 1] - row_start[i] + 15) >> 4;
}

__global__ __launch_bounds__(256) void k_scan3w(const int* __restrict__ tcnt,
                                                const int* __restrict__ bsum,
                                                int* __restrict__ tstart) {
  __shared__ int s[256];
  int i = blockIdx.x * 256 + threadIdx.x;
  int v = (i < N_NODES) ? tcnt[i] : 0;
  s[threadIdx.x] = v;
  __syncthreads();
  for (int o = 1; o < 256; o <<= 1) {
    int t = (threadIdx.x >= o) ? s[threadIdx.x - o] : 0;
    __syncthreads();
    s[threadIdx.x] += t;
    __syncthreads();
  }
  if (i < N_NODES) {
    tstart[i] = s[threadIdx.x] - v + bsum[blockIdx.x];
    if (i == N_NODES - 1) tstart[N_NODES] = s[threadIdx.x] + bsum[blockIdx.x];
  }
}

__global__ __launch_bounds__(256) void k_wfill(const int* __restrict__ row_start,
                                               const int* __restrict__ tstart,
                                               int* __restrict__ wnode, int* __restrict__ wbase) {
  int n = blockIdx.x * 256 + threadIdx.x;
  if (n >= N_NODES) return;
  int rs = row_start[n], re = row_start[n + 1];
  int ts = tstart[n];
  int nt = (re - rs + 15) >> 4;
  for (int mt = 0; mt < nt; ++mt) {
    wnode[ts + mt] = n;
    wbase[ts + mt] = rs + mt * 16;
  }
}

__global__ void k_wpad(const int* __restrict__ tstart,
                       int* __restrict__ wnode, int* __restrict__ wbase) {
  int t = threadIdx.x;  // 64
  int nwi = tstart[N_NODES];
  wnode[nwi + t] = 0;
  wbase[nwi + t] = 0;
}

// ---------------- zero boundary-node rows of aggr ----------------
__global__ __launch_bounds__(256) void k_zbound(const int* __restrict__ tstart,
                                                const int* __restrict__ wnode,
                                                float* __restrict__ aggr) {
  int idx = blockIdx.x * 256 + threadIdx.x;      // [0, EGRID*2*128)
  int seg = idx >> 7, c = idx & 127;
  int b = seg >> 1;
  int NWI = tstart[N_NODES];
  int C = (NWI + EGRID - 1) / EGRID;
  int k0 = b * C;
  if (k0 >= NWI) return;
  int kpos = (seg & 1) ? min(k0 + C - 1, NWI - 1) : k0;
  int node = wnode[kpos];
  aggr[(size_t)node * HID + c] = 0.f;
}

// ---------------- one-time: gather edge_attr into CSR order as bf16 ----------------
__global__ __launch_bounds__(256) void k_gatherA(const float* __restrict__ eattr,
                                                 const int* __restrict__ eids,
                                                 u16* __restrict__ Ae) {
  int t = blockIdx.x * 256 + threadIdx.x;
  if (t >= (N_EDGES + 64) * 8) return;
  int pos = t >> 3, chunk = t & 7;
  short8* dst = (short8*)((char*)Ae + ((size_t)pos << 7) + (chunk << 4));
  if (pos >= N_EDGES) {
    union { short8 s; u32 u[4]; } z; z.u[0] = z.u[1] = z.u[2] = z.u[3] = 0;
    *dst = z.s;
    return;
  }
  int eid = eids[pos];
  const float* src = eattr + ((size_t)eid << 6) + (chunk << 3);
  float4 a = *(const float4*)src;
  float4 b = *(const float4*)(src + 4);
  *dst = cvt8(a, b);
}

// ---------------- W node-part frag pack, ALL layers (pre-scaled by log2e) ----------------
__global__ __launch_bounds__(256) void k_prepW(const float* __restrict__ Wf,
                                               const float* __restrict__ Ws,
                                               u16* __restrict__ Whi, u16* __restrict__ Wlo) {
  int t = blockIdx.x * 256 + threadIdx.x;
  if (t >= 65536 * NCONV) return;
  int l = t >> 16, t16 = t & 65535;
  int c = t16 >> 7, k = t16 & 127;
  int q = c >> 7, col = c & 127;
  const float* W = ((q < 2) ? Wf : Ws) + (size_t)l * 320 * HID;
  int row = (q & 1) ? (128 + k) : k;
  float wv = W[row * HID + col] * LOG2E;
  u16 hb16 = f2bf(wv);
  float lo = wv - __uint_as_float((u32)hb16 << 16);
  int nt = (c >> 4) & 7, l15 = c & 15;
  int s = k >> 5, lg = (k >> 3) & 3, i = k & 7;
  int idx = l * 65536 + (((q * 8 + nt) * 4 + s) * 64 + (lg * 16 + l15)) * 8 + i;
  Whi[idx] = hb16;
  Wlo[idx] = f2bf(lo);
}

// ---------------- W edge-part frag pack, ALL layers (single bf16, pre-scaled) ----------------
__global__ __launch_bounds__(256) void k_prepB(const float* __restrict__ Wf,
                                               const float* __restrict__ Ws,
                                               u16* __restrict__ Bhi) {
  int t = blockIdx.x * 256 + threadIdx.x;
  if (t >= 16384 * NCONV) return;
  int l = t >> 14, tid = t & 16383;
  int i = tid & 7, lane = (tid >> 3) & 63, s = (tid >> 9) & 1, nt = tid >> 10;
  int k = s * 32 + ((lane >> 4) << 3) + i;
  int col = ((nt & 7) << 4) + (lane & 15);
  const float* W = ((nt < 8) ? Wf : Ws) + (size_t)l * 320 * HID + 256 * HID;
  Bhi[t] = f2bf(W[k * HID + col] * LOG2E);
}

// ---------------- node projection GEMM via MFMA: 32 nodes/block ----------------
__global__ __launch_bounds__(256) void k_nodeproj_mfma(
    const u16* __restrict__ hb, const u16* __restrict__ hlo,
    const u16* __restrict__ Whi, const u16* __restrict__ Wlo,
    const float* __restrict__ bf_l, const float* __restrict__ bs_l,
    float* __restrict__ Pd, u32* __restrict__ Ppk) {
  const int lane = threadIdx.x & 63, w = threadIdx.x >> 6;
  const int l15 = lane & 15, lg = lane >> 4;
  const int nb = blockIdx.x * 32;
  const short8* WH = (const short8*)Whi;
  const short8* WL = (const short8*)Wlo;
  f32x4 acc[2][8];
#pragma unroll
  for (int m = 0; m < 2; m++)
#pragma unroll
    for (int nt = 0; nt < 8; nt++) acc[m][nt] = (f32x4){0.f, 0.f, 0.f, 0.f};
  const u32 arow0 = ((u32)(nb + l15)) << 8;
  const u32 arow1 = ((u32)(nb + 16 + l15)) << 8;
#pragma unroll
  for (int s = 0; s < 4; s++) {
    u32 ao0 = arow0 + (s << 6) + (lg << 4);
    u32 ao1 = arow1 + (s << 6) + (lg << 4);
    short8 ah0 = *(const short8*)((const char*)hb + ao0);
    short8 al0 = *(const short8*)((const char*)hlo + ao0);
    short8 ah1 = *(const short8*)((const char*)hb + ao1);
    short8 al1 = *(const short8*)((const char*)hlo + ao1);
#pragma unroll
    for (int nt = 0; nt < 8; nt++) {
      int bi = ((w * 8 + nt) * 4 + s) * 64 + lane;
      short8 bhv = WH[bi];
      short8 blv = WL[bi];
      acc[0][nt] = MFMA16(ah0, bhv, acc[0][nt]);
      acc[0][nt] = MFMA16(ah0, blv, acc[0][nt]);
      acc[0][nt] = MFMA16(al0, bhv, acc[0][nt]);
      acc[1][nt] = MFMA16(ah1, bhv, acc[1][nt]);
      acc[1][nt] = MFMA16(ah1, blv, acc[1][nt]);
      acc[1][nt] = MFMA16(al1, bhv, acc[1][nt]);
    }
  }
  if ((w & 1) == 0) {  // w0 -> Fdst, w2 -> Gdst (f32 + scaled bias)
    const float* bias = (w == 0) ? bf_l : bs_l;
    int pdoff = (w == 0) ? 0 : 128;
#pragma unroll
    for (int m = 0; m < 2; m++) {
#pragma unroll
      for (int nt = 0; nt < 8; nt++) {
        int col = nt * 16 + l15;
        float b = bias[col] * LOG2E;
#pragma unroll
        for (int r = 0; r < 4; r++) {
          int node = nb + m * 16 + lg * 4 + r;
          Pd[(size_t)node * 256 + pdoff + col] = acc[m][nt][r] + b;
        }
      }
    }
  } else {             // w1 -> Fsrc (.x words), w3 -> Gsrc (.y words)
    int off = (w == 1) ? 0 : 1;
#pragma unroll
    for (int m = 0; m < 2; m++) {
#pragma unroll
      for (int g = 0; g < 4; g++) {
#pragma unroll
        for (int r = 0; r < 4; r++) {
          int node = nb + m * 16 + lg * 4 + r;
          Ppk[(size_t)node * 128 + 2 * (g * 16 + l15) + off] =
              f2bf_pack(acc[m][2 * g][r], acc[m][2 * g + 1][r]);
        }
      }
    }
  }
}

// ---------------- worklist edge kernel ----------------
__global__ __launch_bounds__(256, 5) void k_edge_wl(
    const float* __restrict__ Pd, const u32* __restrict__ Ppk,
    const u16* __restrict__ Ae, const int* __restrict__ row_start,
    const int* __restrict__ esrc, const u16* __restrict__ Bhi,
    const int* __restrict__ wnode, const int* __restrict__ wbase,
    const int* __restrict__ tstart, float* __restrict__ aggr) {
  const int tid = threadIdx.x;
  const int lane = tid & 63;
  const int w = tid >> 6;
  const int l15 = lane & 15, lg = lane >> 4;
  const int cb = w * 32;

  const int NWI = tstart[N_NODES];
  int C = (NWI + (int)gridDim.x - 1) / (int)gridDim.x;
  int k0 = (int)blockIdx.x * C;
  int k1 = min(k0 + C, NWI);
  if (k0 >= k1) return;

  const short8* BH = (const short8*)Bhi;
  short8 bh[4][2];
  const int nts[4] = {2 * w, 2 * w + 1, 8 + 2 * w, 9 + 2 * w};
#pragma unroll
  for (int t = 0; t < 4; t++) {
#pragma unroll
    for (int s = 0; s < 2; s++) bh[t][s] = BH[(nts[t] * 2 + s) * 64 + lane];
  }

  const u32 poff = ((u32)(w * 16 + l15)) << 3;
  const int eoff = lg << 2;
  const char* aeb = (const char*)Ae;
  const char* ppb = (const char*)Ppk;

  // ---- prologue ----
  int wn0 = wnode[k0],     wb0 = wbase[k0];
  int wn1 = wnode[k0 + 1], wb1 = wbase[k0 + 1];
  int wn2 = wnode[k0 + 2], wb2 = wbase[k0 + 2];
  int re0 = row_start[wn0 + 1];
  const float* Pn0 = Pd + (size_t)wn0 * 256;
  float fd0 = Pn0[cb + l15], fd1 = Pn0[cb + 16 + l15];
  float gd0 = Pn0[128 + cb + l15], gd1 = Pn0[128 + cb + 16 + l15];
  uint2 gc0, gc1, gc2, gc3;
  {
    int4 sv = *(const int4*)(esrc + wb0 + eoff);
    gc0 = *(const uint2*)(ppb + (((u32)sv.x) << 9) + poff);
    gc1 = *(const uint2*)(ppb + (((u32)sv.y) << 9) + poff);
    gc2 = *(const uint2*)(ppb + (((u32)sv.z) << 9) + poff);
    gc3 = *(const uint2*)(ppb + (((u32)sv.w) << 9) + poff);
  }
  int4 sA = *(const int4*)(esrc + wb1 + eoff);   // S(k0+1)
  u32 ab = ((u32)(wb0 + l15) << 7) + ((u32)lg << 4);
  short8 ac0 = *(const short8*)(aeb + ab);       // A(k0)
  short8 ac1 = *(const short8*)(aeb + ab + 64);

  float acc0 = 0.f, acc1 = 0.f;
  bool first = true;

  for (int k = k0; k < k1; ++k) {
    // G(k+1) from S(k+1) (loaded last iter)
    uint2 gn0 = *(const uint2*)(ppb + (((u32)sA.x) << 9) + poff);
    uint2 gn1 = *(const uint2*)(ppb + (((u32)sA.y) << 9) + poff);
    uint2 gn2 = *(const uint2*)(ppb + (((u32)sA.z) << 9) + poff);
    uint2 gn3 = *(const uint2*)(ppb + (((u32)sA.w) << 9) + poff);
    // wn/wb(k+3)
    int wn3 = wnode[k + 3], wb3 = wbase[k + 3];
    // S(k+2)
    int4 sN = *(const int4*)(esrc + wb2 + eoff);
    // Pd/re(k+1)
    int re1 = row_start[wn1 + 1];
    const float* Pn1 = Pd + (size_t)wn1 * 256;
    float nfd0 = Pn1[cb + l15], nfd1 = Pn1[cb + 16 + l15];
    float ngd0 = Pn1[128 + cb + l15], ngd1 = Pn1[128 + cb + 16 + l15];

    f32x4 d0 = {fd0, fd0, fd0, fd0};
    f32x4 d1 = {fd1, fd1, fd1, fd1};
    f32x4 d2 = {gd0, gd0, gd0, gd0};
    f32x4 d3 = {gd1, gd1, gd1, gd1};
    d0 = MFMA16(ac0, bh[0][0], d0); d0 = MFMA16(ac1, bh[0][1], d0);
    d1 = MFMA16(ac0, bh[1][0], d1); d1 = MFMA16(ac1, bh[1][1], d1);
    d2 = MFMA16(ac0, bh[2][0], d2); d2 = MFMA16(ac1, bh[2][1], d2);
    d3 = MFMA16(ac0, bh[3][0], d3); d3 = MFMA16(ac1, bh[3][1], d3);

    // A(k+1) into same regs
    u32 ab1 = ((u32)(wb1 + l15) << 7) + ((u32)lg << 4);
    ac0 = *(const short8*)(aeb + ab1);
    ac1 = *(const short8*)(aeb + ab1 + 64);

    int rowlim = re0 - wb0;
    bool fullt = (rowlim >= 16);
#pragma unroll
    for (int r = 0; r < 4; r++) {
      uint2 pg = (r == 0) ? gc0 : (r == 1) ? gc1 : (r == 2) ? gc2 : gc3;
      float f0 = d0[r] + __uint_as_float(pg.x << 16);
      float f1 = d1[r] + __uint_as_float(pg.x & 0xffff0000u);
      float g0 = d2[r] + __uint_as_float(pg.y << 16);
      float g1 = d3[r] + __uint_as_float(pg.y & 0xffff0000u);
      float m0 = fsig2(f0) * fsp2(g0);
      float m1 = fsig2(f1) * fsp2(g1);
      if (!fullt) {
        int row = (lg << 2) + r;
        if (row >= rowlim) { m0 = 0.f; m1 = 0.f; }
      }
      acc0 += m0;
      acc1 += m1;
    }

    // segment flush (wave-uniform condition)
    if (wn0 != wn1 || k == k1 - 1) {
      acc0 += __shfl_xor(acc0, 16); acc0 += __shfl_xor(acc0, 32);
      acc1 += __shfl_xor(acc1, 16); acc1 += __shfl_xor(acc1, 32);
      acc0 *= LN2; acc1 *= LN2;   // undo log2e scaling of softplus
      bool shared = first || (k == k1 - 1);
      if (lane < 16) {
        float* p = &aggr[(size_t)wn0 * HID + cb + lane];
        if (shared) atomicAdd(p, acc0); else *p = acc0;
      } else if (lane < 32) {
        float* p = &aggr[(size_t)wn0 * HID + cb + 16 + l15];
        if (shared) atomicAdd(p, acc1); else *p = acc1;
      }
      acc0 = 0.f; acc1 = 0.f;
      first = false;
    }

    // rotate pipeline
    wn0 = wn1; wb0 = wb1; wn1 = wn2; wb1 = wb2; wn2 = wn3; wb2 = wb3;
    re0 = re1;
    fd0 = nfd0; fd1 = nfd1; gd0 = ngd0; gd1 = ngd1;
    gc0 = gn0; gc1 = gn1; gc2 = gn2; gc3 = gn3;
    sA = sN;
  }
}

// ---------------- mean + residual + BN stats (vectorized float4) ----------------
__global__ __launch_bounds__(256) void k_stats(float* __restrict__ hconv,
                                               const float* __restrict__ h,
                                               const float* __restrict__ inv,
                                               float* __restrict__ stats) {
  __shared__ float sb[512];
  int c4 = (threadIdx.x & 31) << 2;   // channel base (mod 128)
  float s1[4] = {0.f, 0.f, 0.f, 0.f}, s2[4] = {0.f, 0.f, 0.f, 0.f};
  const int total4 = N_NODES * HID / 4;
  for (int i = blockIdx.x * 256 + threadIdx.x; i < total4; i += gridDim.x * 256) {
    float4 hv = ((const float4*)hconv)[i];
    float4 rv = ((const float4*)h)[i];
    float iv = inv[i >> 5];
    hv.x = hv.x * iv + rv.x; hv.y = hv.y * iv + rv.y;
    hv.z = hv.z * iv + rv.z; hv.w = hv.w * iv + rv.w;
    ((float4*)hconv)[i] = hv;
    s1[0] += hv.x; s1[1] += hv.y; s1[2] += hv.z; s1[3] += hv.w;
    s2[0] += hv.x * hv.x; s2[1] += hv.y * hv.y; s2[2] += hv.z * hv.z; s2[3] += hv.w * hv.w;
  }
  // channel of s1[j] = c4 + j (constant per thread)
#pragma unroll
  for (int j = 0; j < 4; j++) {
    sb[threadIdx.x] = s1[j];
    sb[256 + threadIdx.x] = s2[j];
    __syncthreads();
    if (threadIdx.x < 32) {
      float a1 = 0.f, a2 = 0.f;
#pragma unroll
      for (int t = 0; t < 8; t++) {
        a1 += sb[threadIdx.x + 32 * t];
        a2 += sb[256 + threadIdx.x + 32 * t];
      }
      atomicAdd(&stats[(threadIdx.x << 2) + j], a1);
      atomicAdd(&stats[128 + (threadIdx.x << 2) + j], a2);
    }
    __syncthreads();
  }
}

// ---------------- BN apply + relu + residual (vectorized) ----------------
__global__ __launch_bounds__(256) void k_bn3(const float* __restrict__ hconv, float* __restrict__ h,
                                             const float* __restrict__ stats,
                                             const float* __restrict__ gamma,
                                             const float* __restrict__ beta,
                                             u16* __restrict__ hb, u16* __restrict__ hlo) {
  __shared__ float ssl[256];
  int t = threadIdx.x;
  if (t < 128) {
    float mu = stats[t] * (1.f / N_NODES);
    float var = stats[128 + t] * (1.f / N_NODES) - mu * mu;
    float sc = gamma[t] * rsqrtf(var + 1e-5f);
    ssl[t] = sc;
    ssl[128 + t] = beta[t] - mu * sc;
  }
  __syncthreads();
  int i = blockIdx.x * 256 + t;            // float4 index
  if (i >= N_NODES * HID / 4) return;
  int c4 = (i << 2) & 127;
  float4 hv = ((const float4*)hconv)[i];
  float4 rv = ((const float4*)h)[i];
  float4 o;
  o.x = fmaxf(hv.x * ssl[c4 + 0] + ssl[128 + c4 + 0], 0.f) + rv.x;
  o.y = fmaxf(hv.y * ssl[c4 + 1] + ssl[128 + c4 + 1], 0.f) + rv.y;
  o.z = fmaxf(hv.z * ssl[c4 + 2] + ssl[128 + c4 + 2], 0.f) + rv.z;
  o.w = fmaxf(hv.w * ssl[c4 + 3] + ssl[128 + c4 + 3], 0.f) + rv.w;
  ((float4*)h)[i] = o;
  u16 b0 = f2bf(o.x), b1 = f2bf(o.y), b2 = f2bf(o.z), b3 = f2bf(o.w);
  ushort4 hv4 = {b0, b1, b2, b3};
  ((ushort4*)hb)[i] = hv4;
  ushort4 lv4;
  lv4.x = f2bf(o.x - __uint_as_float((u32)b0 << 16));
  lv4.y = f2bf(o.y - __uint_as_float((u32)b1 << 16));
  lv4.z = f2bf(o.z - __uint_as_float((u32)b2 << 16));
  lv4.w = f2bf(o.w - __uint_as_float((u32)b3 << 16));
  ((ushort4*)hlo)[i] = lv4;
}

// ---------------- pooling ----------------
__global__ __launch_bounds__(128) void k_pool(const float* __restrict__ h, const int* __restrict__ batch,
                                              float* __restrict__ pooled) {
  int g = blockIdx.x;
  int c = threadIdx.x;
  int lo = 0, hi = N_NODES;
  while (lo < hi) { int m = (lo + hi) >> 1; if (batch[m] < g) lo = m + 1; else hi = m; }
  int s = lo;
  lo = 0; hi = N_NODES;
  while (lo < hi) { int m = (lo + hi) >> 1; if (batch[m] < g + 1) lo = m + 1; else hi = m; }
  int e = lo;
  float acc = 0.f;
  for (int n = s; n < e; n++) acc += h[(size_t)n * HID + c];
  pooled[(size_t)g * HID + c] = acc / (float)max(e - s, 1);
}

// ---------------- head ----------------
__global__ __launch_bounds__(64) void k_head(const float* __restrict__ pooled, const float* __restrict__ W1,
                                             const float* __restrict__ b1, const float* __restrict__ W2,
                                             const float* __restrict__ b2, float* __restrict__ out) {
  int g = blockIdx.x;
  int j = threadIdx.x;
  float acc = b1[j];
#pragma unroll 16
  for (int k = 0; k < 128; k++) acc = fmaf(pooled[(size_t)g * HID + k], W1[k * 64 + j], acc);
  float z = fmaxf(acc, 0.f) + __logf(1.f + __expf(-fabsf(acc)));
  float v = z * W2[j];
  for (int o = 32; o > 0; o >>= 1) v += __shfl_down(v, o);
  if (j == 0) out[g] = v + b2[0];
}

extern "C" void kernel_launch(void* const* d_in, const int* in_sizes, int n_in,
                              void* d_out, int out_size, void* d_ws, size_t ws_size,
                              hipStream_t stream) {
  const float* x     = (const float*)d_in[0];
  const int*   ei    = (const int*)d_in[1];
  const float* eattr = (const float*)d_in[2];
  const int*   batch = (const int*)d_in[3];
  const float* Wemb  = (const float*)d_in[4];
  const float* bemb  = (const float*)d_in[5];
  const float* Wf    = (const float*)d_in[6];
  const float* bf    = (const float*)d_in[7];
  const float* Ws    = (const float*)d_in[8];
  const float* bs    = (const float*)d_in[9];
  const float* gamma = (const float*)d_in[10];
  const float* beta  = (const float*)d_in[11];
  const float* W1    = (const float*)d_in[12];
  const float* b1    = (const float*)d_in[13];
  const float* W2    = (const float*)d_in[14];
  const float* b2    = (const float*)d_in[15];
  float* out = (float*)d_out;

  char* ws = (char*)d_ws;
  size_t off = 0;
  auto alloc = [&](size_t bytes) -> char* {
    char* p = ws + off;
    off += (bytes + 255) & ~(size_t)255;
    return p;
  };
  float* h         = (float*)alloc((size_t)N_NODES * HID * 4);
  u16*   hb        = (u16*)alloc((size_t)NPAD * HID * 2);
  u16*   hlo       = (u16*)alloc((size_t)NPAD * HID * 2);
  float* Pd        = (float*)alloc((size_t)NPAD * 256 * 4);
  u32*   Ppk       = (u32*)alloc((size_t)NPAD * 128 * 4);
  float* hconv     = (float*)alloc((size_t)N_NODES * HID * 4);
  int*   row_start = (int*)alloc((size_t)(N_NODES + 1) * 4);
  float* inv       = (float*)alloc((size_t)N_NODES * 4);
  int*   eids      = (int*)alloc((size_t)(N_EDGES + 64) * 4);
  int*   esrc      = (int*)alloc((size_t)(N_EDGES + 64) * 4);
  u16*   Ae        = (u16*)alloc((size_t)(N_EDGES + 64) * EDIM * 2);
  u16*   Bhi       = (u16*)alloc((size_t)16384 * NCONV * 2);
  u16*   Whi       = (u16*)alloc((size_t)65536 * NCONV * 2);
  u16*   Wlo       = (u16*)alloc((size_t)65536 * NCONV * 2);
  int*   tcnt      = (int*)alloc((size_t)N_NODES * 4);
  int*   tstart    = (int*)alloc((size_t)(N_NODES + 1) * 4);
  int*   wnode     = (int*)alloc((size_t)MAXWI * 4);
  int*   wbase     = (int*)alloc((size_t)MAXWI * 4);
  int*   bsum2     = (int*)alloc(256 * 4);
  char*  zbase     = ws + off;   // ---- zeroed region start ----
  int*   cnt       = (int*)alloc((size_t)N_NODES * 4);
  int*   cur       = (int*)alloc((size_t)N_NODES * 4);
  float* stats     = (float*)alloc((size_t)NCONV * 256 * 4);
  size_t zbytes    = (size_t)((ws + off) - zbase);
  int*   bsum      = (int*)alloc(256 * 4);
  float* pooled    = (float*)alloc((size_t)NGRAPH * HID * 4);
  (void)ws_size; (void)in_sizes; (void)n_in; (void)out_size;

  hipMemsetAsync(zbase, 0, zbytes, stream);

  k_embed<<<(N_NODES * HID + 255) / 256, 256, 0, stream>>>(x, Wemb, bemb, h, hb, hlo);

  k_count<<<(N_EDGES + 255) / 256, 256, 0, stream>>>(ei, cnt);
  int nb = (N_NODES + 255) / 256;  // 196
  k_scan1<<<nb, 256, 0, stream>>>(cnt, bsum);
  k_scan2<<<1, 256, 0, stream>>>(bsum, nb);
  k_scan3<<<nb, 256, 0, stream>>>(cnt, bsum, row_start, inv);
  k_fill<<<(N_EDGES + 255) / 256, 256, 0, stream>>>(ei, row_start, cur, eids, esrc);
  k_gatherA<<<((N_EDGES + 64) * 8 + 255) / 256, 256, 0, stream>>>(eattr, eids, Ae);

  // worklist build
  k_tilecnt<<<nb, 256, 0, stream>>>(row_start, tcnt);
  k_scan1<<<nb, 256, 0, stream>>>(tcnt, bsum2);
  k_scan2<<<1, 256, 0, stream>>>(bsum2, nb);
  k_scan3w<<<nb, 256, 0, stream>>>(tcnt, bsum2, tstart);
  k_wfill<<<nb, 256, 0, stream>>>(row_start, tstart, wnode, wbase);
  k_wpad<<<1, 64, 0, stream>>>(tstart, wnode, wbase);

  k_prepW<<<65536 * NCONV / 256, 256, 0, stream>>>(Wf, Ws, Whi, Wlo);
  k_prepB<<<16384 * NCONV / 256, 256, 0, stream>>>(Wf, Ws, Bhi);

  for (int l = 0; l < NCONV; l++) {
    k_nodeproj_mfma<<<(N_NODES + 31) / 32, 256, 0, stream>>>(hb, hlo,
                                                      Whi + l * 65536, Wlo + l * 65536,
                                                      bf + l * HID, bs + l * HID, Pd, Ppk);
    k_zbound<<<(EGRID * 2 * 128 + 255) / 256, 256, 0, stream>>>(tstart, wnode, hconv);
    k_edge_wl<<<EGRID, 256, 0, stream>>>(Pd, Ppk, Ae, row_start, esrc,
                                         Bhi + l * 16384, wnode, wbase, tstart, hconv);
    k_stats<<<2048, 256, 0, stream>>>(hconv, h, inv, stats + l * 256);
    k_bn3<<<(N_NODES * HID / 4 + 255) / 256, 256, 0, stream>>>(hconv, h, stats + l * 256,
                                                               gamma + l * HID, beta + l * HID,
                                                               hb, hlo);
  }

  k_pool<<<NGRAPH, HID, 0, stream>>>(h, batch, pooled);
  k_head<<<NGRAPH, 64, 0, stream>>>(pooled, W1, b1, W2, b2, out);
}

// Round 18
// 1783.838 us; speedup vs baseline: 1.3237x; 1.3237x over previous
//
#include <hip/hip_runtime.h>
#include <math.h>

#define N_NODES 50000
#define N_EDGES 1600000
#define NGRAPH  512
#define HID     128
#define EDIM    64
#define NCONV   4
#define MAXWI   150064   // max worklist entries (E/16 + N) + pad
#define NPAD    (N_NODES + 32)   // padded node count for nodeproj overrun
#define EGRID   2560     // edge kernel grid
#define LOG2E   1.4426950408889634f
#define LN2     0.6931471805599453f

typedef __attribute__((ext_vector_type(8))) short short8;
typedef __attribute__((ext_vector_type(4))) float f32x4;
typedef unsigned int  u32;
typedef unsigned short u16;

#define MFMA16(a, b, c) __builtin_amdgcn_mfma_f32_16x16x32_bf16(a, b, c, 0, 0, 0)

// inputs pre-scaled by log2e
__device__ __forceinline__ float fsig2(float x) {
  return __builtin_amdgcn_rcpf(1.f + __builtin_amdgcn_exp2f(-x));
}
__device__ __forceinline__ float fsp2(float x) {   // = log2e * softplus(x/log2e)
  return fmaxf(x, 0.f) + __builtin_amdgcn_logf(1.f + __builtin_amdgcn_exp2f(-fabsf(x)));
}
__device__ __forceinline__ u16 f2bf(float x) {
  u32 u = __float_as_uint(x);
  return (u16)((u + 0x7fff + ((u >> 16) & 1)) >> 16);
}
__device__ __forceinline__ u32 f2bf_pack(float lo, float hi) {
  u32 a = __float_as_uint(lo), b = __float_as_uint(hi);
  u32 ra = (a + 0x7fff + ((a >> 16) & 1)) >> 16;
  u32 rb = (b + 0x7fff + ((b >> 16) & 1)) & 0xffff0000u;
  return ra | rb;
}
__device__ __forceinline__ short8 cvt8(float4 a, float4 b) {
  union { short8 s; u32 u[4]; } r;
  r.u[0] = f2bf_pack(a.x, a.y);
  r.u[1] = f2bf_pack(a.z, a.w);
  r.u[2] = f2bf_pack(b.x, b.y);
  r.u[3] = f2bf_pack(b.z, b.w);
  return r.s;
}

// ---------------- embed ----------------
__global__ __launch_bounds__(256) void k_embed(const float* __restrict__ x,
                                               const float* __restrict__ Wemb,
                                               const float* __restrict__ bemb,
                                               float* __restrict__ h,
                                               u16* __restrict__ hb, u16* __restrict__ hlo) {
  int i = blockIdx.x * blockDim.x + threadIdx.x;
  if (i >= N_NODES * HID) return;
  int n = i >> 7, c = i & 127;
  const float* xr = x + (size_t)n * 9;
  float acc = bemb[c];
#pragma unroll
  for (int k = 0; k < 9; k++) acc = fmaf(xr[k], Wemb[k * HID + c], acc);
  h[i] = acc;
  u16 hi16 = f2bf(acc);
  hb[i] = hi16;
  hlo[i] = f2bf(acc - __uint_as_float((u32)hi16 << 16));
}

// ---------------- CSR build ----------------
__global__ __launch_bounds__(256) void k_count(const int* __restrict__ ei, int* __restrict__ cnt) {
  int e = blockIdx.x * blockDim.x + threadIdx.x;
  if (e >= N_EDGES) return;
  atomicAdd(&cnt[ei[N_EDGES + e]], 1);
}

__global__ __launch_bounds__(256) void k_scan1(const int* __restrict__ cnt, int* __restrict__ bsum) {
  __shared__ int s[256];
  int i = blockIdx.x * 256 + threadIdx.x;
  s[threadIdx.x] = (i < N_NODES) ? cnt[i] : 0;
  __syncthreads();
  for (int o = 128; o > 0; o >>= 1) {
    if (threadIdx.x < o) s[threadIdx.x] += s[threadIdx.x + o];
    __syncthreads();
  }
  if (threadIdx.x == 0) bsum[blockIdx.x] = s[0];
}

__global__ __launch_bounds__(256) void k_scan2(int* __restrict__ bsum, int nb) {
  __shared__ int s[256];
  int tid = threadIdx.x;
  s[tid] = (tid < nb) ? bsum[tid] : 0;
  __syncthreads();
  for (int o = 1; o < 256; o <<= 1) {
    int t = (tid >= o) ? s[tid - o] : 0;
    __syncthreads();
    s[tid] += t;
    __syncthreads();
  }
  if (tid < nb) bsum[tid] = (tid == 0) ? 0 : s[tid - 1];
}

__global__ __launch_bounds__(256) void k_scan3(const int* __restrict__ cnt, const int* __restrict__ bsum,
                                               int* __restrict__ row_start, float* __restrict__ inv) {
  __shared__ int s[256];
  int i = blockIdx.x * 256 + threadIdx.x;
  int v = (i < N_NODES) ? cnt[i] : 0;
  s[threadIdx.x] = v;
  __syncthreads();
  for (int o = 1; o < 256; o <<= 1) {
    int t = (threadIdx.x >= o) ? s[threadIdx.x - o] : 0;
    __syncthreads();
    s[threadIdx.x] += t;
    __syncthreads();
  }
  if (i < N_NODES) {
    row_start[i + 1] = s[threadIdx.x] + bsum[blockIdx.x];
    inv[i] = 1.0f / (float)max(v, 1);
    if (i == 0) row_start[0] = 0;
  }
}

__global__ __launch_bounds__(256) void k_fill(const int* __restrict__ ei, const int* __restrict__ row_start,
                                              int* __restrict__ cur, int* __restrict__ eids,
                                              int* __restrict__ esrc) {
  int e = blockIdx.x * blockDim.x + threadIdx.x;
  if (e < 64) {
    eids[N_EDGES + e] = 0;
    esrc[N_EDGES + e] = 0;
  }
  if (e >= N_EDGES) return;
  int s = ei[e], d = ei[N_EDGES + e];
  int pos = row_start[d] + atomicAdd(&cur[d], 1);
  eids[pos] = e;
  esrc[pos] = s;
}

// ---------------- worklist build ----------------
__global__ __launch_bounds__(256) void k_tilecnt(const int* __restrict__ row_start,
                                                 int* __restrict__ tcnt) {
  int i = blockIdx.x * 256 + threadIdx.x;
  if (i >= N_NODES) return;
  tcnt[i] = (row_start[i + 1] - row_start[i] + 15) >> 4;
}

__global__ __launch_bounds__(256) void k_scan3w(const int* __restrict__ tcnt,
                                                const int* __restrict__ bsum,
                                                int* __restrict__ tstart) {
  __shared__ int s[256];
  int i = blockIdx.x * 256 + threadIdx.x;
  int v = (i < N_NODES) ? tcnt[i] : 0;
  s[threadIdx.x] = v;
  __syncthreads();
  for (int o = 1; o < 256; o <<= 1) {
    int t = (threadIdx.x >= o) ? s[threadIdx.x - o] : 0;
    __syncthreads();
    s[threadIdx.x] += t;
    __syncthreads();
  }
  if (i < N_NODES) {
    tstart[i] = s[threadIdx.x] - v + bsum[blockIdx.x];
    if (i == N_NODES - 1) tstart[N_NODES] = s[threadIdx.x] + bsum[blockIdx.x];
  }
}

__global__ __launch_bounds__(256) void k_wfill(const int* __restrict__ row_start,
                                               const int* __restrict__ tstart,
                                               int* __restrict__ wnode, int* __restrict__ wbase) {
  int n = blockIdx.x * 256 + threadIdx.x;
  if (n >= N_NODES) return;
  int rs = row_start[n], re = row_start[n + 1];
  int ts = tstart[n];
  int nt = (re - rs + 15) >> 4;
  for (int mt = 0; mt < nt; ++mt) {
    wnode[ts + mt] = n;
    wbase[ts + mt] = rs + mt * 16;
  }
}

__global__ void k_wpad(const int* __restrict__ tstart,
                       int* __restrict__ wnode, int* __restrict__ wbase) {
  int t = threadIdx.x;  // 64
  int nwi = tstart[N_NODES];
  wnode[nwi + t] = 0;
  wbase[nwi + t] = 0;
}

// ---------------- zero boundary-node rows of aggr ----------------
__global__ __launch_bounds__(256) void k_zbound(const int* __restrict__ tstart,
                                                const int* __restrict__ wnode,
                                                float* __restrict__ aggr) {
  int idx = blockIdx.x * 256 + threadIdx.x;      // [0, EGRID*2*128)
  int seg = idx >> 7, c = idx & 127;
  int b = seg >> 1;
  int NWI = tstart[N_NODES];
  int C = (NWI + EGRID - 1) / EGRID;
  int k0 = b * C;
  if (k0 >= NWI) return;
  int kpos = (seg & 1) ? min(k0 + C - 1, NWI - 1) : k0;
  int node = wnode[kpos];
  aggr[(size_t)node * HID + c] = 0.f;
}

// ---------------- one-time: gather edge_attr into CSR order as bf16 ----------------
__global__ __launch_bounds__(256) void k_gatherA(const float* __restrict__ eattr,
                                                 const int* __restrict__ eids,
                                                 u16* __restrict__ Ae) {
  int t = blockIdx.x * 256 + threadIdx.x;
  if (t >= (N_EDGES + 64) * 8) return;
  int pos = t >> 3, chunk = t & 7;
  short8* dst = (short8*)((char*)Ae + ((size_t)pos << 7) + (chunk << 4));
  if (pos >= N_EDGES) {
    union { short8 s; u32 u[4]; } z; z.u[0] = z.u[1] = z.u[2] = z.u[3] = 0;
    *dst = z.s;
    return;
  }
  int eid = eids[pos];
  const float* src = eattr + ((size_t)eid << 6) + (chunk << 3);
  float4 a = *(const float4*)src;
  float4 b = *(const float4*)(src + 4);
  *dst = cvt8(a, b);
}

// ---------------- W node-part frag pack, ALL layers (pre-scaled by log2e) ----------------
__global__ __launch_bounds__(256) void k_prepW(const float* __restrict__ Wf,
                                               const float* __restrict__ Ws,
                                               u16* __restrict__ Whi, u16* __restrict__ Wlo) {
  int t = blockIdx.x * 256 + threadIdx.x;
  if (t >= 65536 * NCONV) return;
  int l = t >> 16, t16 = t & 65535;
  int c = t16 >> 7, k = t16 & 127;
  int q = c >> 7, col = c & 127;
  const float* W = ((q < 2) ? Wf : Ws) + (size_t)l * 320 * HID;
  int row = (q & 1) ? (128 + k) : k;
  float wv = W[row * HID + col] * LOG2E;
  u16 hb16 = f2bf(wv);
  float lo = wv - __uint_as_float((u32)hb16 << 16);
  int nt = (c >> 4) & 7, l15 = c & 15;
  int s = k >> 5, lg = (k >> 3) & 3, i = k & 7;
  int idx = l * 65536 + (((q * 8 + nt) * 4 + s) * 64 + (lg * 16 + l15)) * 8 + i;
  Whi[idx] = hb16;
  Wlo[idx] = f2bf(lo);
}

// ---------------- W edge-part frag pack, ALL layers (single bf16, pre-scaled) ----------------
__global__ __launch_bounds__(256) void k_prepB(const float* __restrict__ Wf,
                                               const float* __restrict__ Ws,
                                               u16* __restrict__ Bhi) {
  int t = blockIdx.x * 256 + threadIdx.x;
  if (t >= 16384 * NCONV) return;
  int l = t >> 14, tid = t & 16383;
  int i = tid & 7, lane = (tid >> 3) & 63, s = (tid >> 9) & 1, nt = tid >> 10;
  int k = s * 32 + ((lane >> 4) << 3) + i;
  int col = ((nt & 7) << 4) + (lane & 15);
  const float* W = ((nt < 8) ? Wf : Ws) + (size_t)l * 320 * HID + 256 * HID;
  Bhi[t] = f2bf(W[k * HID + col] * LOG2E);
}

// ---------------- node projection GEMM via MFMA: 32 nodes/block ----------------
__global__ __launch_bounds__(256) void k_nodeproj_mfma(
    const u16* __restrict__ hb, const u16* __restrict__ hlo,
    const u16* __restrict__ Whi, const u16* __restrict__ Wlo,
    const float* __restrict__ bf_l, const float* __restrict__ bs_l,
    float* __restrict__ Pd, u32* __restrict__ Ppk) {
  const int lane = threadIdx.x & 63, w = threadIdx.x >> 6;
  const int l15 = lane & 15, lg = lane >> 4;
  const int nb = blockIdx.x * 32;
  const short8* WH = (const short8*)Whi;
  const short8* WL = (const short8*)Wlo;
  f32x4 acc[2][8];
#pragma unroll
  for (int m = 0; m < 2; m++)
#pragma unroll
    for (int nt = 0; nt < 8; nt++) acc[m][nt] = (f32x4){0.f, 0.f, 0.f, 0.f};
  const u32 arow0 = ((u32)(nb + l15)) << 8;
  const u32 arow1 = ((u32)(nb + 16 + l15)) << 8;
#pragma unroll
  for (int s = 0; s < 4; s++) {
    u32 ao0 = arow0 + (s << 6) + (lg << 4);
    u32 ao1 = arow1 + (s << 6) + (lg << 4);
    short8 ah0 = *(const short8*)((const char*)hb + ao0);
    short8 al0 = *(const short8*)((const char*)hlo + ao0);
    short8 ah1 = *(const short8*)((const char*)hb + ao1);
    short8 al1 = *(const short8*)((const char*)hlo + ao1);
#pragma unroll
    for (int nt = 0; nt < 8; nt++) {
      int bi = ((w * 8 + nt) * 4 + s) * 64 + lane;
      short8 bhv = WH[bi];
      short8 blv = WL[bi];
      acc[0][nt] = MFMA16(ah0, bhv, acc[0][nt]);
      acc[0][nt] = MFMA16(ah0, blv, acc[0][nt]);
      acc[0][nt] = MFMA16(al0, bhv, acc[0][nt]);
      acc[1][nt] = MFMA16(ah1, bhv, acc[1][nt]);
      acc[1][nt] = MFMA16(ah1, blv, acc[1][nt]);
      acc[1][nt] = MFMA16(al1, bhv, acc[1][nt]);
    }
  }
  if ((w & 1) == 0) {  // w0 -> Fdst, w2 -> Gdst (f32 + scaled bias)
    const float* bias = (w == 0) ? bf_l : bs_l;
    int pdoff = (w == 0) ? 0 : 128;
#pragma unroll
    for (int m = 0; m < 2; m++) {
#pragma unroll
      for (int nt = 0; nt < 8; nt++) {
        int col = nt * 16 + l15;
        float b = bias[col] * LOG2E;
#pragma unroll
        for (int r = 0; r < 4; r++) {
          int node = nb + m * 16 + lg * 4 + r;
          Pd[(size_t)node * 256 + pdoff + col] = acc[m][nt][r] + b;
        }
      }
    }
  } else {             // w1 -> Fsrc (.x words), w3 -> Gsrc (.y words)
    int off = (w == 1) ? 0 : 1;
#pragma unroll
    for (int m = 0; m < 2; m++) {
#pragma unroll
      for (int g = 0; g < 4; g++) {
#pragma unroll
        for (int r = 0; r < 4; r++) {
          int node = nb + m * 16 + lg * 4 + r;
          Ppk[(size_t)node * 128 + 2 * (g * 16 + l15) + off] =
              f2bf_pack(acc[m][2 * g][r], acc[m][2 * g + 1][r]);
        }
      }
    }
  }
}

// ---------------- worklist edge kernel (exp2 domain) ----------------
__global__ __launch_bounds__(256, 5) void k_edge_wl(
    const float* __restrict__ Pd, const u32* __restrict__ Ppk,
    const u16* __restrict__ Ae, const int* __restrict__ row_start,
    const int* __restrict__ esrc, const u16* __restrict__ Bhi,
    const int* __restrict__ wnode, const int* __restrict__ wbase,
    const int* __restrict__ tstart, float* __restrict__ aggr) {
  const int tid = threadIdx.x;
  const int lane = tid & 63;
  const int w = tid >> 6;
  const int l15 = lane & 15, lg = lane >> 4;
  const int cb = w * 32;

  const int NWI = tstart[N_NODES];
  int C = (NWI + (int)gridDim.x - 1) / (int)gridDim.x;
  int k0 = (int)blockIdx.x * C;
  int k1 = min(k0 + C, NWI);
  if (k0 >= k1) return;

  const short8* BH = (const short8*)Bhi;
  short8 bh[4][2];
  const int nts[4] = {2 * w, 2 * w + 1, 8 + 2 * w, 9 + 2 * w};
#pragma unroll
  for (int t = 0; t < 4; t++) {
#pragma unroll
    for (int s = 0; s < 2; s++) bh[t][s] = BH[(nts[t] * 2 + s) * 64 + lane];
  }

  const u32 poff = ((u32)(w * 16 + l15)) << 3;
  const int eoff = lg << 2;
  const char* aeb = (const char*)Ae;
  const char* ppb = (const char*)Ppk;

  // ---- prologue ----
  int wn0 = wnode[k0],     wb0 = wbase[k0];
  int wn1 = wnode[k0 + 1], wb1 = wbase[k0 + 1];
  int wn2 = wnode[k0 + 2], wb2 = wbase[k0 + 2];
  int re0 = row_start[wn0 + 1];
  const float* Pn0 = Pd + (size_t)wn0 * 256;
  float fd0 = Pn0[cb + l15], fd1 = Pn0[cb + 16 + l15];
  float gd0 = Pn0[128 + cb + l15], gd1 = Pn0[128 + cb + 16 + l15];
  uint2 gc0, gc1, gc2, gc3;
  {
    int4 sv = *(const int4*)(esrc + wb0 + eoff);
    gc0 = *(const uint2*)(ppb + (((u32)sv.x) << 9) + poff);
    gc1 = *(const uint2*)(ppb + (((u32)sv.y) << 9) + poff);
    gc2 = *(const uint2*)(ppb + (((u32)sv.z) << 9) + poff);
    gc3 = *(const uint2*)(ppb + (((u32)sv.w) << 9) + poff);
  }
  int4 sA = *(const int4*)(esrc + wb1 + eoff);   // S(k0+1)
  u32 ab = ((u32)(wb0 + l15) << 7) + ((u32)lg << 4);
  short8 ac0 = *(const short8*)(aeb + ab);       // A(k0)
  short8 ac1 = *(const short8*)(aeb + ab + 64);

  float acc0 = 0.f, acc1 = 0.f;
  bool first = true;

  for (int k = k0; k < k1; ++k) {
    // G(k+1) from S(k+1) (loaded last iter)
    uint2 gn0 = *(const uint2*)(ppb + (((u32)sA.x) << 9) + poff);
    uint2 gn1 = *(const uint2*)(ppb + (((u32)sA.y) << 9) + poff);
    uint2 gn2 = *(const uint2*)(ppb + (((u32)sA.z) << 9) + poff);
    uint2 gn3 = *(const uint2*)(ppb + (((u32)sA.w) << 9) + poff);
    // wn/wb(k+3)
    int wn3 = wnode[k + 3], wb3 = wbase[k + 3];
    // S(k+2)
    int4 sN = *(const int4*)(esrc + wb2 + eoff);
    // Pd/re(k+1)
    int re1 = row_start[wn1 + 1];
    const float* Pn1 = Pd + (size_t)wn1 * 256;
    float nfd0 = Pn1[cb + l15], nfd1 = Pn1[cb + 16 + l15];
    float ngd0 = Pn1[128 + cb + l15], ngd1 = Pn1[128 + cb + 16 + l15];

    f32x4 d0 = {fd0, fd0, fd0, fd0};
    f32x4 d1 = {fd1, fd1, fd1, fd1};
    f32x4 d2 = {gd0, gd0, gd0, gd0};
    f32x4 d3 = {gd1, gd1, gd1, gd1};
    d0 = MFMA16(ac0, bh[0][0], d0); d0 = MFMA16(ac1, bh[0][1], d0);
    d1 = MFMA16(ac0, bh[1][0], d1); d1 = MFMA16(ac1, bh[1][1], d1);
    d2 = MFMA16(ac0, bh[2][0], d2); d2 = MFMA16(ac1, bh[2][1], d2);
    d3 = MFMA16(ac0, bh[3][0], d3); d3 = MFMA16(ac1, bh[3][1], d3);

    // A(k+1) into same regs
    u32 ab1 = ((u32)(wb1 + l15) << 7) + ((u32)lg << 4);
    ac0 = *(const short8*)(aeb + ab1);
    ac1 = *(const short8*)(aeb + ab1 + 64);

    int rowlim = re0 - wb0;
    bool fullt = (rowlim >= 16);
#pragma unroll
    for (int r = 0; r < 4; r++) {
      uint2 pg = (r == 0) ? gc0 : (r == 1) ? gc1 : (r == 2) ? gc2 : gc3;
      float f0 = d0[r] + __uint_as_float(pg.x << 16);
      float f1 = d1[r] + __uint_as_float(pg.x & 0xffff0000u);
      float g0 = d2[r] + __uint_as_float(pg.y << 16);
      float g1 = d3[r] + __uint_as_float(pg.y & 0xffff0000u);
      float m0 = fsig2(f0) * fsp2(g0);
      float m1 = fsig2(f1) * fsp2(g1);
      if (!fullt) {
        int row = (lg << 2) + r;
        if (row >= rowlim) { m0 = 0.f; m1 = 0.f; }
      }
      acc0 += m0;
      acc1 += m1;
    }

    // segment flush (wave-uniform condition)
    if (wn0 != wn1 || k == k1 - 1) {
      acc0 += __shfl_xor(acc0, 16); acc0 += __shfl_xor(acc0, 32);
      acc1 += __shfl_xor(acc1, 16); acc1 += __shfl_xor(acc1, 32);
      acc0 *= LN2; acc1 *= LN2;   // undo log2e scaling of softplus
      bool shared = first || (k == k1 - 1);
      if (lane < 16) {
        float* p = &aggr[(size_t)wn0 * HID + cb + lane];
        if (shared) atomicAdd(p, acc0); else *p = acc0;
      } else if (lane < 32) {
        float* p = &aggr[(size_t)wn0 * HID + cb + 16 + l15];
        if (shared) atomicAdd(p, acc1); else *p = acc1;
      }
      acc0 = 0.f; acc1 = 0.f;
      first = false;
    }

    // rotate pipeline
    wn0 = wn1; wb0 = wb1; wn1 = wn2; wb1 = wb2; wn2 = wn3; wb2 = wb3;
    re0 = re1;
    fd0 = nfd0; fd1 = nfd1; gd0 = ngd0; gd1 = ngd1;
    gc0 = gn0; gc1 = gn1; gc2 = gn2; gc3 = gn3;
    sA = sN;
  }
}

// ---------------- mean + residual + BN stats (R16 proven version) ----------------
__global__ __launch_bounds__(256) void k_stats(float* __restrict__ hconv,
                                               const float* __restrict__ h,
                                               const float* __restrict__ inv,
                                               float* __restrict__ stats) {
  __shared__ float sb[512];
  int c = threadIdx.x & 127;
  float s1 = 0.f, s2 = 0.f;
  for (int i = blockIdx.x * 256 + threadIdx.x; i < N_NODES * HID; i += gridDim.x * 256) {
    float v = hconv[i] * inv[i >> 7] + h[i];
    hconv[i] = v;
    s1 += v;
    s2 += v * v;
  }
  sb[threadIdx.x] = s1;
  sb[256 + threadIdx.x] = s2;
  __syncthreads();
  if (threadIdx.x < 128) {
    atomicAdd(&stats[c], sb[threadIdx.x] + sb[threadIdx.x + 128]);
    atomicAdd(&stats[128 + c], sb[256 + threadIdx.x] + sb[256 + threadIdx.x + 128]);
  }
}

// ---------------- BN apply + relu + residual (R16 proven version) ----------------
__global__ __launch_bounds__(256) void k_bn3(const float* __restrict__ hconv, float* __restrict__ h,
                                             const float* __restrict__ stats,
                                             const float* __restrict__ gamma,
                                             const float* __restrict__ beta,
                                             u16* __restrict__ hb, u16* __restrict__ hlo) {
  __shared__ float ssl[256];
  int t = threadIdx.x;
  if (t < 128) {
    float mu = stats[t] * (1.f / N_NODES);
    float var = stats[128 + t] * (1.f / N_NODES) - mu * mu;
    float sc = gamma[t] * rsqrtf(var + 1e-5f);
    ssl[t] = sc;
    ssl[128 + t] = beta[t] - mu * sc;
  }
  __syncthreads();
  int i = blockIdx.x * 256 + t;
  if (i >= N_NODES * HID) return;
  int c = i & 127;
  float v = hconv[i] * ssl[c] + ssl[128 + c];
  float hn = fmaxf(v, 0.f) + h[i];
  h[i] = hn;
  u16 hi16 = f2bf(hn);
  hb[i] = hi16;
  hlo[i] = f2bf(hn - __uint_as_float((u32)hi16 << 16));
}

// ---------------- pooling ----------------
__global__ __launch_bounds__(128) void k_pool(const float* __restrict__ h, const int* __restrict__ batch,
                                              float* __restrict__ pooled) {
  int g = blockIdx.x;
  int c = threadIdx.x;
  int lo = 0, hi = N_NODES;
  while (lo < hi) { int m = (lo + hi) >> 1; if (batch[m] < g) lo = m + 1; else hi = m; }
  int s = lo;
  lo = 0; hi = N_NODES;
  while (lo < hi) { int m = (lo + hi) >> 1; if (batch[m] < g + 1) lo = m + 1; else hi = m; }
  int e = lo;
  float acc = 0.f;
  for (int n = s; n < e; n++) acc += h[(size_t)n * HID + c];
  pooled[(size_t)g * HID + c] = acc / (float)max(e - s, 1);
}

// ---------------- head ----------------
__global__ __launch_bounds__(64) void k_head(const float* __restrict__ pooled, const float* __restrict__ W1,
                                             const float* __restrict__ b1, const float* __restrict__ W2,
                                             const float* __restrict__ b2, float* __restrict__ out) {
  int g = blockIdx.x;
  int j = threadIdx.x;
  float acc = b1[j];
#pragma unroll 16
  for (int k = 0; k < 128; k++) acc = fmaf(pooled[(size_t)g * HID + k], W1[k * 64 + j], acc);
  float z = fmaxf(acc, 0.f) + __logf(1.f + __expf(-fabsf(acc)));
  float v = z * W2[j];
  for (int o = 32; o > 0; o >>= 1) v += __shfl_down(v, o);
  if (j == 0) out[g] = v + b2[0];
}

extern "C" void kernel_launch(void* const* d_in, const int* in_sizes, int n_in,
                              void* d_out, int out_size, void* d_ws, size_t ws_size,
                              hipStream_t stream) {
  const float* x     = (const float*)d_in[0];
  const int*   ei    = (const int*)d_in[1];
  const float* eattr = (const float*)d_in[2];
  const int*   batch = (const int*)d_in[3];
  const float* Wemb  = (const float*)d_in[4];
  const float* bemb  = (const float*)d_in[5];
  const float* Wf    = (const float*)d_in[6];
  const float* bf    = (const float*)d_in[7];
  const float* Ws    = (const float*)d_in[8];
  const float* bs    = (const float*)d_in[9];
  const float* gamma = (const float*)d_in[10];
  const float* beta  = (const float*)d_in[11];
  const float* W1    = (const float*)d_in[12];
  const float* b1    = (const float*)d_in[13];
  const float* W2    = (const float*)d_in[14];
  const float* b2    = (const float*)d_in[15];
  float* out = (float*)d_out;

  char* ws = (char*)d_ws;
  size_t off = 0;
  auto alloc = [&](size_t bytes) -> char* {
    char* p = ws + off;
    off += (bytes + 255) & ~(size_t)255;
    return p;
  };
  float* h         = (float*)alloc((size_t)N_NODES * HID * 4);
  u16*   hb        = (u16*)alloc((size_t)NPAD * HID * 2);
  u16*   hlo       = (u16*)alloc((size_t)NPAD * HID * 2);
  float* Pd        = (float*)alloc((size_t)NPAD * 256 * 4);
  u32*   Ppk       = (u32*)alloc((size_t)NPAD * 128 * 4);
  float* hconv     = (float*)alloc((size_t)N_NODES * HID * 4);
  int*   row_start = (int*)alloc((size_t)(N_NODES + 1) * 4);
  float* inv       = (float*)alloc((size_t)N_NODES * 4);
  int*   eids      = (int*)alloc((size_t)(N_EDGES + 64) * 4);
  int*   esrc      = (int*)alloc((size_t)(N_EDGES + 64) * 4);
  u16*   Ae        = (u16*)alloc((size_t)(N_EDGES + 64) * EDIM * 2);
  u16*   Bhi       = (u16*)alloc((size_t)16384 * NCONV * 2);
  u16*   Whi       = (u16*)alloc((size_t)65536 * NCONV * 2);
  u16*   Wlo       = (u16*)alloc((size_t)65536 * NCONV * 2);
  int*   tcnt      = (int*)alloc((size_t)N_NODES * 4);
  int*   tstart    = (int*)alloc((size_t)(N_NODES + 1) * 4);
  int*   wnode     = (int*)alloc((size_t)MAXWI * 4);
  int*   wbase     = (int*)alloc((size_t)MAXWI * 4);
  int*   bsum2     = (int*)alloc(256 * 4);
  char*  zbase     = ws + off;   // ---- zeroed region start ----
  int*   cnt       = (int*)alloc((size_t)N_NODES * 4);
  int*   cur       = (int*)alloc((size_t)N_NODES * 4);
  float* stats     = (float*)alloc((size_t)NCONV * 256 * 4);
  size_t zbytes    = (size_t)((ws + off) - zbase);
  int*   bsum      = (int*)alloc(256 * 4);
  float* pooled    = (float*)alloc((size_t)NGRAPH * HID * 4);
  (void)ws_size; (void)in_sizes; (void)n_in; (void)out_size;

  hipMemsetAsync(zbase, 0, zbytes, stream);

  k_embed<<<(N_NODES * HID + 255) / 256, 256, 0, stream>>>(x, Wemb, bemb, h, hb, hlo);

  k_count<<<(N_EDGES + 255) / 256, 256, 0, stream>>>(ei, cnt);
  int nb = (N_NODES + 255) / 256;  // 196
  k_scan1<<<nb, 256, 0, stream>>>(cnt, bsum);
  k_scan2<<<1, 256, 0, stream>>>(bsum, nb);
  k_scan3<<<nb, 256, 0, stream>>>(cnt, bsum, row_start, inv);
  k_fill<<<(N_EDGES + 255) / 256, 256, 0, stream>>>(ei, row_start, cur, eids, esrc);
  k_gatherA<<<((N_EDGES + 64) * 8 + 255) / 256, 256, 0, stream>>>(eattr, eids, Ae);

  // worklist build
  k_tilecnt<<<nb, 256, 0, stream>>>(row_start, tcnt);
  k_scan1<<<nb, 256, 0, stream>>>(tcnt, bsum2);
  k_scan2<<<1, 256, 0, stream>>>(bsum2, nb);
  k_scan3w<<<nb, 256, 0, stream>>>(tcnt, bsum2, tstart);
  k_wfill<<<nb, 256, 0, stream>>>(row_start, tstart, wnode, wbase);
  k_wpad<<<1, 64, 0, stream>>>(tstart, wnode, wbase);

  k_prepW<<<65536 * NCONV / 256, 256, 0, stream>>>(Wf, Ws, Whi, Wlo);
  k_prepB<<<16384 * NCONV / 256, 256, 0, stream>>>(Wf, Ws, Bhi);

  for (int l = 0; l < NCONV; l++) {
    k_nodeproj_mfma<<<(N_NODES + 31) / 32, 256, 0, stream>>>(hb, hlo,
                                                      Whi + l * 65536, Wlo + l * 65536,
                                                      bf + l * HID, bs + l * HID, Pd, Ppk);
    k_zbound<<<(EGRID * 2 * 128 + 255) / 256, 256, 0, stream>>>(tstart, wnode, hconv);
    k_edge_wl<<<EGRID, 256, 0, stream>>>(Pd, Ppk, Ae, row_start, esrc,
                                         Bhi + l * 16384, wnode, wbase, tstart, hconv);
    k_stats<<<2048, 256, 0, stream>>>(hconv, h, inv, stats + l * 256);
    k_bn3<<<(N_NODES * HID + 255) / 256, 256, 0, stream>>>(hconv, h, stats + l * 256,
                                                           gamma + l * HID, beta + l * HID,
                                                           hb, hlo);
  }

  k_pool<<<NGRAPH, HID, 0, stream>>>(h, batch, pooled);
  k_head<<<NGRAPH, 64, 0, stream>>>(pooled, W1, b1, W2, b2, out);
}

// Round 19
// 1768.673 us; speedup vs baseline: 1.3351x; 1.0086x over previous
//
#include <hip/hip_runtime.h>
#include <math.h>

#define N_NODES 50000
#define N_EDGES 1600000
#define NGRAPH  512
#define HID     128
#define EDIM    64
#define NCONV   4
#define MAXWI   150064   // max worklist entries (E/16 + N) + pad
#define NPAD    (N_NODES + 32)   // padded node count for nodeproj overrun
#define EGRID   2560     // edge kernel grid
#define LOG2E   1.4426950408889634f
#define LN2     0.6931471805599453f

typedef __attribute__((ext_vector_type(8))) short short8;
typedef __attribute__((ext_vector_type(4))) float f32x4;
typedef unsigned int  u32;
typedef unsigned short u16;

#define MFMA16(a, b, c) __builtin_amdgcn_mfma_f32_16x16x32_bf16(a, b, c, 0, 0, 0)

// inputs pre-scaled by log2e
__device__ __forceinline__ float fsig2(float x) {
  return __builtin_amdgcn_rcpf(1.f + __builtin_amdgcn_exp2f(-x));
}
__device__ __forceinline__ float fsp2(float x) {   // = log2e * softplus(x/log2e)
  return fmaxf(x, 0.f) + __builtin_amdgcn_logf(1.f + __builtin_amdgcn_exp2f(-fabsf(x)));
}
__device__ __forceinline__ u16 f2bf(float x) {
  u32 u = __float_as_uint(x);
  return (u16)((u + 0x7fff + ((u >> 16) & 1)) >> 16);
}
__device__ __forceinline__ u32 f2bf_pack(float lo, float hi) {
  u32 a = __float_as_uint(lo), b = __float_as_uint(hi);
  u32 ra = (a + 0x7fff + ((a >> 16) & 1)) >> 16;
  u32 rb = (b + 0x7fff + ((b >> 16) & 1)) & 0xffff0000u;
  return ra | rb;
}
__device__ __forceinline__ short8 cvt8(float4 a, float4 b) {
  union { short8 s; u32 u[4]; } r;
  r.u[0] = f2bf_pack(a.x, a.y);
  r.u[1] = f2bf_pack(a.z, a.w);
  r.u[2] = f2bf_pack(b.x, b.y);
  r.u[3] = f2bf_pack(b.z, b.w);
  return r.s;
}

// ---------------- embed ----------------
__global__ __launch_bounds__(256) void k_embed(const float* __restrict__ x,
                                               const float* __restrict__ Wemb,
                                               const float* __restrict__ bemb,
                                               float* __restrict__ h,
                                               u16* __restrict__ hb, u16* __restrict__ hlo) {
  int i = blockIdx.x * blockDim.x + threadIdx.x;
  if (i >= N_NODES * HID) return;
  int n = i >> 7, c = i & 127;
  const float* xr = x + (size_t)n * 9;
  float acc = bemb[c];
#pragma unroll
  for (int k = 0; k < 9; k++) acc = fmaf(xr[k], Wemb[k * HID + c], acc);
  h[i] = acc;
  u16 hi16 = f2bf(acc);
  hb[i] = hi16;
  hlo[i] = f2bf(acc - __uint_as_float((u32)hi16 << 16));
}

// ---------------- CSR build ----------------
__global__ __launch_bounds__(256) void k_count(const int* __restrict__ ei, int* __restrict__ cnt) {
  int e = blockIdx.x * blockDim.x + threadIdx.x;
  if (e >= N_EDGES) return;
  atomicAdd(&cnt[ei[N_EDGES + e]], 1);
}

__global__ __launch_bounds__(256) void k_scan1(const int* __restrict__ cnt, int* __restrict__ bsum) {
  __shared__ int s[256];
  int i = blockIdx.x * 256 + threadIdx.x;
  s[threadIdx.x] = (i < N_NODES) ? cnt[i] : 0;
  __syncthreads();
  for (int o = 128; o > 0; o >>= 1) {
    if (threadIdx.x < o) s[threadIdx.x] += s[threadIdx.x + o];
    __syncthreads();
  }
  if (threadIdx.x == 0) bsum[blockIdx.x] = s[0];
}

__global__ __launch_bounds__(256) void k_scan2(int* __restrict__ bsum, int nb) {
  __shared__ int s[256];
  int tid = threadIdx.x;
  s[tid] = (tid < nb) ? bsum[tid] : 0;
  __syncthreads();
  for (int o = 1; o < 256; o <<= 1) {
    int t = (tid >= o) ? s[tid - o] : 0;
    __syncthreads();
    s[tid] += t;
    __syncthreads();
  }
  if (tid < nb) bsum[tid] = (tid == 0) ? 0 : s[tid - 1];
}

__global__ __launch_bounds__(256) void k_scan3(const int* __restrict__ cnt, const int* __restrict__ bsum,
                                               int* __restrict__ row_start, float* __restrict__ inv) {
  __shared__ int s[256];
  int i = blockIdx.x * 256 + threadIdx.x;
  int v = (i < N_NODES) ? cnt[i] : 0;
  s[threadIdx.x] = v;
  __syncthreads();
  for (int o = 1; o < 256; o <<= 1) {
    int t = (threadIdx.x >= o) ? s[threadIdx.x - o] : 0;
    __syncthreads();
    s[threadIdx.x] += t;
    __syncthreads();
  }
  if (i < N_NODES) {
    row_start[i + 1] = s[threadIdx.x] + bsum[blockIdx.x];
    inv[i] = 1.0f / (float)max(v, 1);
    if (i == 0) row_start[0] = 0;
  }
}

__global__ __launch_bounds__(256) void k_fill(const int* __restrict__ ei, const int* __restrict__ row_start,
                                              int* __restrict__ cur, int* __restrict__ eids,
                                              int* __restrict__ esrc) {
  int e = blockIdx.x * blockDim.x + threadIdx.x;
  if (e < 64) {
    eids[N_EDGES + e] = 0;
    esrc[N_EDGES + e] = 0;
  }
  if (e >= N_EDGES) return;
  int s = ei[e], d = ei[N_EDGES + e];
  int pos = row_start[d] + atomicAdd(&cur[d], 1);
  eids[pos] = e;
  esrc[pos] = s;
}

// ---------------- worklist build ----------------
__global__ __launch_bounds__(256) void k_tilecnt(const int* __restrict__ row_start,
                                                 int* __restrict__ tcnt) {
  int i = blockIdx.x * 256 + threadIdx.x;
  if (i >= N_NODES) return;
  tcnt[i] = (row_start[i + 1] - row_start[i] + 15) >> 4;
}

__global__ __launch_bounds__(256) void k_scan3w(const int* __restrict__ tcnt,
                                                const int* __restrict__ bsum,
                                                int* __restrict__ tstart) {
  __shared__ int s[256];
  int i = blockIdx.x * 256 + threadIdx.x;
  int v = (i < N_NODES) ? tcnt[i] : 0;
  s[threadIdx.x] = v;
  __syncthreads();
  for (int o = 1; o < 256; o <<= 1) {
    int t = (threadIdx.x >= o) ? s[threadIdx.x - o] : 0;
    __syncthreads();
    s[threadIdx.x] += t;
    __syncthreads();
  }
  if (i < N_NODES) {
    tstart[i] = s[threadIdx.x] - v + bsum[blockIdx.x];
    if (i == N_NODES - 1) tstart[N_NODES] = s[threadIdx.x] + bsum[blockIdx.x];
  }
}

__global__ __launch_bounds__(256) void k_wfill(const int* __restrict__ row_start,
                                               const int* __restrict__ tstart,
                                               int* __restrict__ wnode, int* __restrict__ wbase) {
  int n = blockIdx.x * 256 + threadIdx.x;
  if (n >= N_NODES) return;
  int rs = row_start[n], re = row_start[n + 1];
  int ts = tstart[n];
  int nt = (re - rs + 15) >> 4;
  for (int mt = 0; mt < nt; ++mt) {
    wnode[ts + mt] = n;
    wbase[ts + mt] = rs + mt * 16;
  }
}

__global__ void k_wpad(const int* __restrict__ tstart,
                       int* __restrict__ wnode, int* __restrict__ wbase) {
  int t = threadIdx.x;  // 64
  int nwi = tstart[N_NODES];
  wnode[nwi + t] = 0;
  wbase[nwi + t] = 0;
}

// ---------------- zero boundary-node rows of aggr ----------------
__global__ __launch_bounds__(256) void k_zbound(const int* __restrict__ tstart,
                                                const int* __restrict__ wnode,
                                                float* __restrict__ aggr) {
  int idx = blockIdx.x * 256 + threadIdx.x;      // [0, EGRID*2*128)
  int seg = idx >> 7, c = idx & 127;
  int b = seg >> 1;
  int NWI = tstart[N_NODES];
  int C = (NWI + EGRID - 1) / EGRID;
  int k0 = b * C;
  if (k0 >= NWI) return;
  int kpos = (seg & 1) ? min(k0 + C - 1, NWI - 1) : k0;
  int node = wnode[kpos];
  aggr[(size_t)node * HID + c] = 0.f;
}

// ---------------- one-time: gather edge_attr into CSR order as bf16 ----------------
__global__ __launch_bounds__(256) void k_gatherA(const float* __restrict__ eattr,
                                                 const int* __restrict__ eids,
                                                 u16* __restrict__ Ae) {
  int t = blockIdx.x * 256 + threadIdx.x;
  if (t >= (N_EDGES + 64) * 8) return;
  int pos = t >> 3, chunk = t & 7;
  short8* dst = (short8*)((char*)Ae + ((size_t)pos << 7) + (chunk << 4));
  if (pos >= N_EDGES) {
    union { short8 s; u32 u[4]; } z; z.u[0] = z.u[1] = z.u[2] = z.u[3] = 0;
    *dst = z.s;
    return;
  }
  int eid = eids[pos];
  const float* src = eattr + ((size_t)eid << 6) + (chunk << 3);
  float4 a = *(const float4*)src;
  float4 b = *(const float4*)(src + 4);
  *dst = cvt8(a, b);
}

// ---------------- W node-part frag pack, ALL layers (pre-scaled by log2e) ----------------
__global__ __launch_bounds__(256) void k_prepW(const float* __restrict__ Wf,
                                               const float* __restrict__ Ws,
                                               u16* __restrict__ Whi, u16* __restrict__ Wlo) {
  int t = blockIdx.x * 256 + threadIdx.x;
  if (t >= 65536 * NCONV) return;
  int l = t >> 16, t16 = t & 65535;
  int c = t16 >> 7, k = t16 & 127;
  int q = c >> 7, col = c & 127;
  const float* W = ((q < 2) ? Wf : Ws) + (size_t)l * 320 * HID;
  int row = (q & 1) ? (128 + k) : k;
  float wv = W[row * HID + col] * LOG2E;
  u16 hb16 = f2bf(wv);
  float lo = wv - __uint_as_float((u32)hb16 << 16);
  int nt = (c >> 4) & 7, l15 = c & 15;
  int s = k >> 5, lg = (k >> 3) & 3, i = k & 7;
  int idx = l * 65536 + (((q * 8 + nt) * 4 + s) * 64 + (lg * 16 + l15)) * 8 + i;
  Whi[idx] = hb16;
  Wlo[idx] = f2bf(lo);
}

// ---------------- W edge-part frag pack, ALL layers (single bf16, pre-scaled) ----------------
__global__ __launch_bounds__(256) void k_prepB(const float* __restrict__ Wf,
                                               const float* __restrict__ Ws,
                                               u16* __restrict__ Bhi) {
  int t = blockIdx.x * 256 + threadIdx.x;
  if (t >= 16384 * NCONV) return;
  int l = t >> 14, tid = t & 16383;
  int i = tid & 7, lane = (tid >> 3) & 63, s = (tid >> 9) & 1, nt = tid >> 10;
  int k = s * 32 + ((lane >> 4) << 3) + i;
  int col = ((nt & 7) << 4) + (lane & 15);
  const float* W = ((nt < 8) ? Wf : Ws) + (size_t)l * 320 * HID + 256 * HID;
  Bhi[t] = f2bf(W[k * HID + col] * LOG2E);
}

// ---------------- node projection GEMM via MFMA: 32 nodes/block ----------------
__global__ __launch_bounds__(256) void k_nodeproj_mfma(
    const u16* __restrict__ hb, const u16* __restrict__ hlo,
    const u16* __restrict__ Whi, const u16* __restrict__ Wlo,
    const float* __restrict__ bf_l, const float* __restrict__ bs_l,
    float* __restrict__ Pd, u32* __restrict__ Ppk) {
  const int lane = threadIdx.x & 63, w = threadIdx.x >> 6;
  const int l15 = lane & 15, lg = lane >> 4;
  const int nb = blockIdx.x * 32;
  const short8* WH = (const short8*)Whi;
  const short8* WL = (const short8*)Wlo;
  f32x4 acc[2][8];
#pragma unroll
  for (int m = 0; m < 2; m++)
#pragma unroll
    for (int nt = 0; nt < 8; nt++) acc[m][nt] = (f32x4){0.f, 0.f, 0.f, 0.f};
  const u32 arow0 = ((u32)(nb + l15)) << 8;
  const u32 arow1 = ((u32)(nb + 16 + l15)) << 8;
#pragma unroll
  for (int s = 0; s < 4; s++) {
    u32 ao0 = arow0 + (s << 6) + (lg << 4);
    u32 ao1 = arow1 + (s << 6) + (lg << 4);
    short8 ah0 = *(const short8*)((const char*)hb + ao0);
    short8 al0 = *(const short8*)((const char*)hlo + ao0);
    short8 ah1 = *(const short8*)((const char*)hb + ao1);
    short8 al1 = *(const short8*)((const char*)hlo + ao1);
#pragma unroll
    for (int nt = 0; nt < 8; nt++) {
      int bi = ((w * 8 + nt) * 4 + s) * 64 + lane;
      short8 bhv = WH[bi];
      short8 blv = WL[bi];
      acc[0][nt] = MFMA16(ah0, bhv, acc[0][nt]);
      acc[0][nt] = MFMA16(ah0, blv, acc[0][nt]);
      acc[0][nt] = MFMA16(al0, bhv, acc[0][nt]);
      acc[1][nt] = MFMA16(ah1, bhv, acc[1][nt]);
      acc[1][nt] = MFMA16(ah1, blv, acc[1][nt]);
      acc[1][nt] = MFMA16(al1, bhv, acc[1][nt]);
    }
  }
  if ((w & 1) == 0) {  // w0 -> Fdst, w2 -> Gdst (f32 + scaled bias)
    const float* bias = (w == 0) ? bf_l : bs_l;
    int pdoff = (w == 0) ? 0 : 128;
#pragma unroll
    for (int m = 0; m < 2; m++) {
#pragma unroll
      for (int nt = 0; nt < 8; nt++) {
        int col = nt * 16 + l15;
        float b = bias[col] * LOG2E;
#pragma unroll
        for (int r = 0; r < 4; r++) {
          int node = nb + m * 16 + lg * 4 + r;
          Pd[(size_t)node * 256 + pdoff + col] = acc[m][nt][r] + b;
        }
      }
    }
  } else {             // w1 -> Fsrc (.x words), w3 -> Gsrc (.y words)
    int off = (w == 1) ? 0 : 1;
#pragma unroll
    for (int m = 0; m < 2; m++) {
#pragma unroll
      for (int g = 0; g < 4; g++) {
#pragma unroll
        for (int r = 0; r < 4; r++) {
          int node = nb + m * 16 + lg * 4 + r;
          Ppk[(size_t)node * 128 + 2 * (g * 16 + l15) + off] =
              f2bf_pack(acc[m][2 * g][r], acc[m][2 * g + 1][r]);
        }
      }
    }
  }
}

// ---------------- worklist edge kernel (exp2 domain) ----------------
__global__ __launch_bounds__(256, 5) void k_edge_wl(
    const float* __restrict__ Pd, const u32* __restrict__ Ppk,
    const u16* __restrict__ Ae, const int* __restrict__ row_start,
    const int* __restrict__ esrc, const u16* __restrict__ Bhi,
    const int* __restrict__ wnode, const int* __restrict__ wbase,
    const int* __restrict__ tstart, float* __restrict__ aggr) {
  const int tid = threadIdx.x;
  const int lane = tid & 63;
  const int w = tid >> 6;
  const int l15 = lane & 15, lg = lane >> 4;
  const int cb = w * 32;

  const int NWI = tstart[N_NODES];
  int C = (NWI + (int)gridDim.x - 1) / (int)gridDim.x;
  int k0 = (int)blockIdx.x * C;
  int k1 = min(k0 + C, NWI);
  if (k0 >= k1) return;

  const short8* BH = (const short8*)Bhi;
  short8 bh[4][2];
  const int nts[4] = {2 * w, 2 * w + 1, 8 + 2 * w, 9 + 2 * w};
#pragma unroll
  for (int t = 0; t < 4; t++) {
#pragma unroll
    for (int s = 0; s < 2; s++) bh[t][s] = BH[(nts[t] * 2 + s) * 64 + lane];
  }

  const u32 poff = ((u32)(w * 16 + l15)) << 3;
  const int eoff = lg << 2;
  const char* aeb = (const char*)Ae;
  const char* ppb = (const char*)Ppk;

  // ---- prologue ----
  int wn0 = wnode[k0],     wb0 = wbase[k0];
  int wn1 = wnode[k0 + 1], wb1 = wbase[k0 + 1];
  int wn2 = wnode[k0 + 2], wb2 = wbase[k0 + 2];
  int re0 = row_start[wn0 + 1];
  const float* Pn0 = Pd + (size_t)wn0 * 256;
  float fd0 = Pn0[cb + l15], fd1 = Pn0[cb + 16 + l15];
  float gd0 = Pn0[128 + cb + l15], gd1 = Pn0[128 + cb + 16 + l15];
  uint2 gc0, gc1, gc2, gc3;
  {
    int4 sv = *(const int4*)(esrc + wb0 + eoff);
    gc0 = *(const uint2*)(ppb + (((u32)sv.x) << 9) + poff);
    gc1 = *(const uint2*)(ppb + (((u32)sv.y) << 9) + poff);
    gc2 = *(const uint2*)(ppb + (((u32)sv.z) << 9) + poff);
    gc3 = *(const uint2*)(ppb + (((u32)sv.w) << 9) + poff);
  }
  int4 sA = *(const int4*)(esrc + wb1 + eoff);   // S(k0+1)
  u32 ab = ((u32)(wb0 + l15) << 7) + ((u32)lg << 4);
  short8 ac0 = *(const short8*)(aeb + ab);       // A(k0)
  short8 ac1 = *(const short8*)(aeb + ab + 64);

  float acc0 = 0.f, acc1 = 0.f;
  bool first = true;

  for (int k = k0; k < k1; ++k) {
    // G(k+1) from S(k+1) (loaded last iter)
    uint2 gn0 = *(const uint2*)(ppb + (((u32)sA.x) << 9) + poff);
    uint2 gn1 = *(const uint2*)(ppb + (((u32)sA.y) << 9) + poff);
    uint2 gn2 = *(const uint2*)(ppb + (((u32)sA.z) << 9) + poff);
    uint2 gn3 = *(const uint2*)(ppb + (((u32)sA.w) << 9) + poff);
    // wn/wb(k+3)
    int wn3 = wnode[k + 3], wb3 = wbase[k + 3];
    // S(k+2)
    int4 sN = *(const int4*)(esrc + wb2 + eoff);
    // Pd/re(k+1)
    int re1 = row_start[wn1 + 1];
    const float* Pn1 = Pd + (size_t)wn1 * 256;
    float nfd0 = Pn1[cb + l15], nfd1 = Pn1[cb + 16 + l15];
    float ngd0 = Pn1[128 + cb + l15], ngd1 = Pn1[128 + cb + 16 + l15];

    f32x4 d0 = {fd0, fd0, fd0, fd0};
    f32x4 d1 = {fd1, fd1, fd1, fd1};
    f32x4 d2 = {gd0, gd0, gd0, gd0};
    f32x4 d3 = {gd1, gd1, gd1, gd1};
    d0 = MFMA16(ac0, bh[0][0], d0); d0 = MFMA16(ac1, bh[0][1], d0);
    d1 = MFMA16(ac0, bh[1][0], d1); d1 = MFMA16(ac1, bh[1][1], d1);
    d2 = MFMA16(ac0, bh[2][0], d2); d2 = MFMA16(ac1, bh[2][1], d2);
    d3 = MFMA16(ac0, bh[3][0], d3); d3 = MFMA16(ac1, bh[3][1], d3);

    // A(k+1) into same regs
    u32 ab1 = ((u32)(wb1 + l15) << 7) + ((u32)lg << 4);
    ac0 = *(const short8*)(aeb + ab1);
    ac1 = *(const short8*)(aeb + ab1 + 64);

    int rowlim = re0 - wb0;
    bool fullt = (rowlim >= 16);
#pragma unroll
    for (int r = 0; r < 4; r++) {
      uint2 pg = (r == 0) ? gc0 : (r == 1) ? gc1 : (r == 2) ? gc2 : gc3;
      float f0 = d0[r] + __uint_as_float(pg.x << 16);
      float f1 = d1[r] + __uint_as_float(pg.x & 0xffff0000u);
      float g0 = d2[r] + __uint_as_float(pg.y << 16);
      float g1 = d3[r] + __uint_as_float(pg.y & 0xffff0000u);
      float m0 = fsig2(f0) * fsp2(g0);
      float m1 = fsig2(f1) * fsp2(g1);
      if (!fullt) {
        int row = (lg << 2) + r;
        if (row >= rowlim) { m0 = 0.f; m1 = 0.f; }
      }
      acc0 += m0;
      acc1 += m1;
    }

    // segment flush (wave-uniform condition)
    if (wn0 != wn1 || k == k1 - 1) {
      acc0 += __shfl_xor(acc0, 16); acc0 += __shfl_xor(acc0, 32);
      acc1 += __shfl_xor(acc1, 16); acc1 += __shfl_xor(acc1, 32);
      acc0 *= LN2; acc1 *= LN2;   // undo log2e scaling of softplus
      bool shared = first || (k == k1 - 1);
      if (lane < 16) {
        float* p = &aggr[(size_t)wn0 * HID + cb + lane];
        if (shared) atomicAdd(p, acc0); else *p = acc0;
      } else if (lane < 32) {
        float* p = &aggr[(size_t)wn0 * HID + cb + 16 + l15];
        if (shared) atomicAdd(p, acc1); else *p = acc1;
      }
      acc0 = 0.f; acc1 = 0.f;
      first = false;
    }

    // rotate pipeline
    wn0 = wn1; wb0 = wb1; wn1 = wn2; wb1 = wb2; wn2 = wn3; wb2 = wb3;
    re0 = re1;
    fd0 = nfd0; fd1 = nfd1; gd0 = ngd0; gd1 = ngd1;
    gc0 = gn0; gc1 = gn1; gc2 = gn2; gc3 = gn3;
    sA = sN;
  }
}

// ---------------- BN stats (read-only: v recomputed, not stored) ----------------
__global__ __launch_bounds__(256) void k_stats(const float* __restrict__ aggr,
                                               const float* __restrict__ h,
                                               const float* __restrict__ inv,
                                               float* __restrict__ stats) {
  __shared__ float sb[512];
  int c = threadIdx.x & 127;
  float s1 = 0.f, s2 = 0.f;
  for (int i = blockIdx.x * 256 + threadIdx.x; i < N_NODES * HID; i += gridDim.x * 256) {
    float v = aggr[i] * inv[i >> 7] + h[i];
    s1 += v;
    s2 += v * v;
  }
  sb[threadIdx.x] = s1;
  sb[256 + threadIdx.x] = s2;
  __syncthreads();
  if (threadIdx.x < 128) {
    atomicAdd(&stats[c], sb[threadIdx.x] + sb[threadIdx.x + 128]);
    atomicAdd(&stats[128 + c], sb[256 + threadIdx.x] + sb[256 + threadIdx.x + 128]);
  }
}

// ---------------- BN apply + relu + residual (recomputes hconv from aggr) ----------------
__global__ __launch_bounds__(256) void k_bn3(const float* __restrict__ aggr, float* __restrict__ h,
                                             const float* __restrict__ inv,
                                             const float* __restrict__ stats,
                                             const float* __restrict__ gamma,
                                             const float* __restrict__ beta,
                                             u16* __restrict__ hb, u16* __restrict__ hlo) {
  __shared__ float ssl[256];
  int t = threadIdx.x;
  if (t < 128) {
    float mu = stats[t] * (1.f / N_NODES);
    float var = stats[128 + t] * (1.f / N_NODES) - mu * mu;
    float sc = gamma[t] * rsqrtf(var + 1e-5f);
    ssl[t] = sc;
    ssl[128 + t] = beta[t] - mu * sc;
  }
  __syncthreads();
  int i = blockIdx.x * 256 + t;
  if (i >= N_NODES * HID) return;
  int c = i & 127;
  float hv = h[i];
  float v = (aggr[i] * inv[i >> 7] + hv) * ssl[c] + ssl[128 + c];
  float hn = fmaxf(v, 0.f) + hv;
  h[i] = hn;
  u16 hi16 = f2bf(hn);
  hb[i] = hi16;
  hlo[i] = f2bf(hn - __uint_as_float((u32)hi16 << 16));
}

// ---------------- fused pooling + head ----------------
__global__ __launch_bounds__(128) void k_poolhead(const float* __restrict__ h,
                                                  const int* __restrict__ batch,
                                                  const float* __restrict__ W1,
                                                  const float* __restrict__ b1,
                                                  const float* __restrict__ W2,
                                                  const float* __restrict__ b2,
                                                  float* __restrict__ out) {
  __shared__ float pl[128];
  int g = blockIdx.x;
  int c = threadIdx.x;
  int lo = 0, hi = N_NODES;
  while (lo < hi) { int m = (lo + hi) >> 1; if (batch[m] < g) lo = m + 1; else hi = m; }
  int s = lo;
  lo = 0; hi = N_NODES;
  while (lo < hi) { int m = (lo + hi) >> 1; if (batch[m] < g + 1) lo = m + 1; else hi = m; }
  int e = lo;
  float acc = 0.f;
  for (int n = s; n < e; n++) acc += h[(size_t)n * HID + c];
  pl[c] = acc / (float)max(e - s, 1);
  __syncthreads();
  if (c < 64) {
    float a = b1[c];
#pragma unroll 16
    for (int k = 0; k < 128; k++) a = fmaf(pl[k], W1[k * 64 + c], a);
    float z = fmaxf(a, 0.f) + __logf(1.f + __expf(-fabsf(a)));
    float v = z * W2[c];
    for (int o = 32; o > 0; o >>= 1) v += __shfl_down(v, o);
    if (c == 0) out[g] = v + b2[0];
  }
}

extern "C" void kernel_launch(void* const* d_in, const int* in_sizes, int n_in,
                              void* d_out, int out_size, void* d_ws, size_t ws_size,
                              hipStream_t stream) {
  const float* x     = (const float*)d_in[0];
  const int*   ei    = (const int*)d_in[1];
  const float* eattr = (const float*)d_in[2];
  const int*   batch = (const int*)d_in[3];
  const float* Wemb  = (const float*)d_in[4];
  const float* bemb  = (const float*)d_in[5];
  const float* Wf    = (const float*)d_in[6];
  const float* bf    = (const float*)d_in[7];
  const float* Ws    = (const float*)d_in[8];
  const float* bs    = (const float*)d_in[9];
  const float* gamma = (const float*)d_in[10];
  const float* beta  = (const float*)d_in[11];
  const float* W1    = (const float*)d_in[12];
  const float* b1    = (const float*)d_in[13];
  const float* W2    = (const float*)d_in[14];
  const float* b2    = (const float*)d_in[15];
  float* out = (float*)d_out;

  char* ws = (char*)d_ws;
  size_t off = 0;
  auto alloc = [&](size_t bytes) -> char* {
    char* p = ws + off;
    off += (bytes + 255) & ~(size_t)255;
    return p;
  };
  float* h         = (float*)alloc((size_t)N_NODES * HID * 4);
  u16*   hb        = (u16*)alloc((size_t)NPAD * HID * 2);
  u16*   hlo       = (u16*)alloc((size_t)NPAD * HID * 2);
  float* Pd        = (float*)alloc((size_t)NPAD * 256 * 4);
  u32*   Ppk       = (u32*)alloc((size_t)NPAD * 128 * 4);
  float* aggr      = (float*)alloc((size_t)N_NODES * HID * 4);
  int*   row_start = (int*)alloc((size_t)(N_NODES + 1) * 4);
  float* inv       = (float*)alloc((size_t)N_NODES * 4);
  int*   eids      = (int*)alloc((size_t)(N_EDGES + 64) * 4);
  int*   esrc      = (int*)alloc((size_t)(N_EDGES + 64) * 4);
  u16*   Ae        = (u16*)alloc((size_t)(N_EDGES + 64) * EDIM * 2);
  u16*   Bhi       = (u16*)alloc((size_t)16384 * NCONV * 2);
  u16*   Whi       = (u16*)alloc((size_t)65536 * NCONV * 2);
  u16*   Wlo       = (u16*)alloc((size_t)65536 * NCONV * 2);
  int*   tcnt      = (int*)alloc((size_t)N_NODES * 4);
  int*   tstart    = (int*)alloc((size_t)(N_NODES + 1) * 4);
  int*   wnode     = (int*)alloc((size_t)MAXWI * 4);
  int*   wbase     = (int*)alloc((size_t)MAXWI * 4);
  int*   bsum2     = (int*)alloc(256 * 4);
  char*  zbase     = ws + off;   // ---- zeroed region start ----
  int*   cnt       = (int*)alloc((size_t)N_NODES * 4);
  int*   cur       = (int*)alloc((size_t)N_NODES * 4);
  float* stats     = (float*)alloc((size_t)NCONV * 256 * 4);
  size_t zbytes    = (size_t)((ws + off) - zbase);
  int*   bsum      = (int*)alloc(256 * 4);
  (void)ws_size; (void)in_sizes; (void)n_in; (void)out_size;

  hipMemsetAsync(zbase, 0, zbytes, stream);

  k_embed<<<(N_NODES * HID + 255) / 256, 256, 0, stream>>>(x, Wemb, bemb, h, hb, hlo);

  k_count<<<(N_EDGES + 255) / 256, 256, 0, stream>>>(ei, cnt);
  int nb = (N_NODES + 255) / 256;  // 196
  k_scan1<<<nb, 256, 0, stream>>>(cnt, bsum);
  k_scan2<<<1, 256, 0, stream>>>(bsum, nb);
  k_scan3<<<nb, 256, 0, stream>>>(cnt, bsum, row_start, inv);
  k_fill<<<(N_EDGES + 255) / 256, 256, 0, stream>>>(ei, row_start, cur, eids, esrc);
  k_gatherA<<<((N_EDGES + 64) * 8 + 255) / 256, 256, 0, stream>>>(eattr, eids, Ae);

  // worklist build
  k_tilecnt<<<nb, 256, 0, stream>>>(row_start, tcnt);
  k_scan1<<<nb, 256, 0, stream>>>(tcnt, bsum2);
  k_scan2<<<1, 256, 0, stream>>>(bsum2, nb);
  k_scan3w<<<nb, 256, 0, stream>>>(tcnt, bsum2, tstart);
  k_wfill<<<nb, 256, 0, stream>>>(row_start, tstart, wnode, wbase);
  k_wpad<<<1, 64, 0, stream>>>(tstart, wnode, wbase);

  k_prepW<<<65536 * NCONV / 256, 256, 0, stream>>>(Wf, Ws, Whi, Wlo);
  k_prepB<<<16384 * NCONV / 256, 256, 0, stream>>>(Wf, Ws, Bhi);

  for (int l = 0; l < NCONV; l++) {
    k_nodeproj_mfma<<<(N_NODES + 31) / 32, 256, 0, stream>>>(hb, hlo,
                                                      Whi + l * 65536, Wlo + l * 65536,
                                                      bf + l * HID, bs + l * HID, Pd, Ppk);
    k_zbound<<<(EGRID * 2 * 128 + 255) / 256, 256, 0, stream>>>(tstart, wnode, aggr);
    k_edge_wl<<<EGRID, 256, 0, stream>>>(Pd, Ppk, Ae, row_start, esrc,
                                         Bhi + l * 16384, wnode, wbase, tstart, aggr);
    k_stats<<<2048, 256, 0, stream>>>(aggr, h, inv, stats + l * 256);
    k_bn3<<<(N_NODES * HID + 255) / 256, 256, 0, stream>>>(aggr, h, inv, stats + l * 256,
                                                           gamma + l * HID, beta + l * HID,
                                                           hb, hlo);
  }

  k_poolhead<<<NGRAPH, 128, 0, stream>>>(h, batch, W1, b1, W2, b2, out);
}